// Round 5
// baseline (915.386 us; speedup 1.0000x reference)
//
#include <hip/hip_runtime.h>

// GAT layer: B=2, N=50000, D=64, H=4, d=16, O=64, E=800000
#define N_NODES 50000
#define N_EDGES 800000
#define N_ROWS 100000           // B*N
#define NEG_SLOPE 0.1f
#define FC_BLOCKS 3125          // 100000 rows / 32 rows per block
#define WS_S 68                 // W row stride (floats), 16B-aligned

static __device__ __forceinline__ float lrelu(float z) {
    return (z > 0.f) ? z : NEG_SLOPE * z;
}

// ---- Kernel 1 (fused): feat = x @ W_fc.T (+ el/er)  ||  dst histogram ------
// fc blocks [0,3125): 32 rows/block; wave rq owns rows rq+{0,4,...,28}; lane j
// is the output column. xs reads are wave-uniform broadcasts (conflict-free).
// hist blocks [3125,6250): one edge per thread, atomicAdd into deg.
__global__ __launch_bounds__(256, 6) void k_fc_hist(
        const float* __restrict__ x, const float* __restrict__ Wfc,
        const float* __restrict__ al, const float* __restrict__ ar,
        float* __restrict__ feat, float* __restrict__ el, float* __restrict__ er,
        const int* __restrict__ dst, int* __restrict__ deg) {
    const int t = threadIdx.x;
    if (blockIdx.x >= FC_BLOCKS) {           // ---- histogram part ----
        const int e = (blockIdx.x - FC_BLOCKS) * 256 + t;   // exact 800000
        atomicAdd(&deg[dst[e]], 1);
        return;
    }
    __shared__ float Ws[64 * WS_S];          // 17.4 KB
    __shared__ float xs[32 * 64];            //  8.2 KB
    const float4* W4 = (const float4*)Wfc;   // [64][16] float4
#pragma unroll
    for (int i = 0; i < 4; ++i) {            // stage W_fc
        const int p = i * 256 + t;
        *(float4*)&Ws[(p >> 4) * WS_S + (p & 15) * 4] = W4[p];
    }
    const float4* x4g = (const float4*)x;    // [100000][16] float4
    const int base4 = blockIdx.x * 512;      // 32 rows x 16 f4
#pragma unroll
    for (int i = 0; i < 2; ++i) {            // stage 32 x-rows
        const int p = i * 256 + t;
        *(float4*)&xs[p * 4] = x4g[base4 + p];
    }
    __syncthreads();

    const int j = t & 63, rq = t >> 6;
    float acc[8] = {};
#pragma unroll
    for (int k4 = 0; k4 < 16; ++k4) {
        const float4 wv = *(const float4*)&Ws[j * WS_S + k4 * 4];
#pragma unroll
        for (int i = 0; i < 8; ++i) {        // broadcast reads, 8 indep chains
            const float4 xv = *(const float4*)&xs[(rq + i * 4) * 64 + k4 * 4];
            acc[i] = fmaf(xv.x, wv.x, acc[i]);
            acc[i] = fmaf(xv.y, wv.y, acc[i]);
            acc[i] = fmaf(xv.z, wv.z, acc[i]);
            acc[i] = fmaf(xv.w, wv.w, acc[i]);
        }
    }

    const float alj = al[j], arj = ar[j];
#pragma unroll
    for (int i = 0; i < 8; ++i) {
        const int m = blockIdx.x * 32 + rq + i * 4;
        const int b = (m >= N_NODES) ? 1 : 0;
        const int n = m - b * N_NODES;
        feat[n * 128 + b * 64 + j] = acc[i];
        float pl = acc[i] * alj, pr = acc[i] * arj;
#pragma unroll
        for (int off = 1; off < 16; off <<= 1) {
            pl += __shfl_xor(pl, off, 16);
            pr += __shfl_xor(pr, off, 16);
        }
        if ((j & 15) == 0) {
            const int h = j >> 4;
            el[n * 8 + b * 4 + h] = pl;
            er[n * 8 + b * 4 + h] = pr;
        }
    }
}

// ---- CSR build --------------------------------------------------------------
__global__ __launch_bounds__(256) void k_alloc(const int* __restrict__ deg,
                                               int* __restrict__ offsets,
                                               int* __restrict__ cursor,
                                               int* __restrict__ gctr) {
    const int i = blockIdx.x * 256 + threadIdx.x;   // grid 196 covers 50176
    const int lane = threadIdx.x & 63;
    const int d = (i < N_NODES) ? deg[i] : 0;
    int incl = d;
#pragma unroll
    for (int off = 1; off < 64; off <<= 1) {
        int v = __shfl_up(incl, off, 64);
        if (lane >= off) incl += v;
    }
    const int wtot = __shfl(incl, 63, 64);
    int wbase = 0;
    if (lane == 63) wbase = atomicAdd(gctr, wtot);
    wbase = __shfl(wbase, 63, 64);
    if (i < N_NODES) {
        const int beg = wbase + incl - d;
        offsets[i] = beg;
        cursor[i] = beg;
    }
}

__global__ __launch_bounds__(256) void k_scatter(const int* __restrict__ src,
                                                 const int* __restrict__ dst,
                                                 const float* __restrict__ w,
                                                 int* __restrict__ cursor,
                                                 int2* __restrict__ srcw) {
    const int e = blockIdx.x * 256 + threadIdx.x;
    const int pos = atomicAdd(&cursor[dst[e]], 1);
    srcw[pos] = make_int2(src[e], __float_as_int(w[e]));
}

// ---- Kernel 2: per-dst gather — softmax numerator + weighted sum ------------
// 32 threads/node, 8 nodes per 256-block; thread owns one float4 (sub 0..31)
__global__ __launch_bounds__(256) void k_gather(const int2* __restrict__ srcw,
                                                const int* __restrict__ offsets,
                                                const int* __restrict__ deg,
                                                const float* __restrict__ el,
                                                const float* __restrict__ er,
                                                const float* __restrict__ feat,
                                                float* __restrict__ denom,
                                                float* __restrict__ rst) {
    const int t = threadIdx.x;
    const int n = blockIdx.x * 8 + (t >> 5);   // grid exact 50000/8
    const int sub = t & 31, c = sub >> 2;
    const int beg = offsets[n], len = deg[n];
    const float ern = er[n * 8 + c];
    const float4* feat4 = (const float4*)feat;
    float4 acc = make_float4(0.f, 0.f, 0.f, 0.f);
    float den = 0.f;
    int k = 0;
    for (; k + 4 <= len; k += 4) {             // 4 independent gather chains
        int2 sw[4];
        float ev[4];
        float4 fv[4];
#pragma unroll
        for (int u = 0; u < 4; ++u) sw[u] = srcw[beg + k + u];
#pragma unroll
        for (int u = 0; u < 4; ++u) ev[u] = el[sw[u].x * 8 + c];
#pragma unroll
        for (int u = 0; u < 4; ++u) fv[u] = feat4[sw[u].x * 32 + sub];
#pragma unroll
        for (int u = 0; u < 4; ++u) {
            const float xx = __expf(__int_as_float(sw[u].y) * lrelu(ev[u] + ern));
            den += xx;
            acc.x = fmaf(xx, fv[u].x, acc.x); acc.y = fmaf(xx, fv[u].y, acc.y);
            acc.z = fmaf(xx, fv[u].z, acc.z); acc.w = fmaf(xx, fv[u].w, acc.w);
        }
    }
    for (; k < len; ++k) {
        const int2 s0 = srcw[beg + k];
        const float e0 = el[s0.x * 8 + c];
        const float4 f0 = feat4[s0.x * 32 + sub];
        const float x0 = __expf(__int_as_float(s0.y) * lrelu(e0 + ern));
        den += x0;
        acc.x = fmaf(x0, f0.x, acc.x); acc.y = fmaf(x0, f0.y, acc.y);
        acc.z = fmaf(x0, f0.z, acc.z); acc.w = fmaf(x0, f0.w, acc.w);
    }
    ((float4*)rst)[n * 32 + sub] = acc;
    if ((sub & 3) == 0) denom[n * 8 + c] = den;
}

// ---- Kernel 3: out = (rst/denom) @ W_out.T + b_out, layout [B,N,H,O] --------
__global__ __launch_bounds__(256) void k_out(const float* __restrict__ rst,
                                             const float* __restrict__ denom,
                                             const float* __restrict__ Wout,
                                             const float* __restrict__ bout,
                                             float* __restrict__ out) {
    __shared__ float rs[1024];
    __shared__ float dn[64];
    const int t = threadIdx.x;
    const int o = t & 63, r = t >> 6;
#pragma unroll
    for (int i = 0; i < 4; ++i)
        rs[i * 256 + t] = rst[blockIdx.x * 1024 + i * 256 + t];
    if (t < 64) dn[t] = denom[blockIdx.x * 64 + t];
    __syncthreads();

    const float4* Wo4 = (const float4*)Wout;
    const float4 wa = Wo4[o * 4 + 0], wb = Wo4[o * 4 + 1];
    const float4 wc = Wo4[o * 4 + 2], wd = Wo4[o * 4 + 3];
    const float bo = bout[o];
#pragma unroll
    for (int i = 0; i < 16; ++i) {
        const int gl = i * 4 + r;              // local g, 0..63
        const float dv = dn[gl];
        const float dinv = (dv > 0.f) ? 1.f / dv : 0.f;
        const float4* r4 = (const float4*)&rs[gl * 16];
        const float4 ra = r4[0], rb = r4[1], rc = r4[2], rd = r4[3];
        float acc = ra.x * wa.x;
        acc = fmaf(ra.y, wa.y, acc); acc = fmaf(ra.z, wa.z, acc); acc = fmaf(ra.w, wa.w, acc);
        acc = fmaf(rb.x, wb.x, acc); acc = fmaf(rb.y, wb.y, acc);
        acc = fmaf(rb.z, wb.z, acc); acc = fmaf(rb.w, wb.w, acc);
        acc = fmaf(rc.x, wc.x, acc); acc = fmaf(rc.y, wc.y, acc);
        acc = fmaf(rc.z, wc.z, acc); acc = fmaf(rc.w, wc.w, acc);
        acc = fmaf(rd.x, wd.x, acc); acc = fmaf(rd.y, wd.y, acc);
        acc = fmaf(rd.z, wd.z, acc); acc = fmaf(rd.w, wd.w, acc);
        acc = fmaf(acc, dinv, bo);
        const int g = blockIdx.x * 64 + gl;    // g = n*8 + b*4 + h
        const int n = g >> 3, b = (g >> 2) & 1, h = g & 3;
        out[b * (N_NODES * 256) + n * 256 + h * 64 + o] = acc;
    }
}

extern "C" void kernel_launch(void* const* d_in, const int* in_sizes, int n_in,
                              void* d_out, int out_size, void* d_ws, size_t ws_size,
                              hipStream_t stream) {
    // setup_inputs order: vt, x, w, src, dst, W_fc, attn_l, attn_r, W_out, b_out
    const float* x    = (const float*)d_in[1];
    const float* w    = (const float*)d_in[2];
    const int*   src  = (const int*)  d_in[3];
    const int*   dst  = (const int*)  d_in[4];
    const float* Wfc  = (const float*)d_in[5];
    const float* al   = (const float*)d_in[6];
    const float* ar   = (const float*)d_in[7];
    const float* Wout = (const float*)d_in[8];
    const float* bout = (const float*)d_in[9];
    float* out = (float*)d_out;

    float* ws    = (float*)d_ws;
    float* feat  = ws;                  // 6,400,000
    float* el    = feat + 6400000;      //   400,000
    float* er    = el + 400000;         //   400,000
    float* denom = er + 400000;         //   400,000
    float* rst   = denom + 400000;      // 6,400,000
    int*   offsets = (int*)(rst + 6400000);   // 50,000
    int*   cursor  = offsets + 50000;         // 50,000
    int*   deg     = cursor + 50000;          // 50,000
    int*   gctr    = deg + 50000;             // 16 (pad)
    int2*  srcw    = (int2*)(gctr + 16);      // 800,000 int2

    hipMemsetAsync(deg, 0, (50000 + 16) * sizeof(int), stream);  // deg + gctr

    k_fc_hist<<<FC_BLOCKS + N_EDGES / 256, 256, 0, stream>>>(
        x, Wfc, al, ar, feat, el, er, dst, deg);
    k_alloc<<<196, 256, 0, stream>>>(deg, offsets, cursor, gctr);
    k_scatter<<<N_EDGES / 256, 256, 0, stream>>>(src, dst, w, cursor, srcw);
    k_gather<<<N_NODES / 8, 256, 0, stream>>>(srcw, offsets, deg, el, er, feat, denom, rst);
    k_out<<<6250, 256, 0, stream>>>(rst, denom, Wout, bout, out);
}